// Round 13
// baseline (2235.764 us; speedup 1.0000x reference)
//
#include <hip/hip_runtime.h>
#include <cfloat>
#include <math.h>

#define B_ 8
#define N_ 4096
#define D_ 64
#define S_ 1024
#define K_ 32
#define CIN_ 131  // 2*D + 3

// Move a u64 across lanes with a constant DPP control (2x 32-bit update_dpp).
template <int CTRL>
__device__ __forceinline__ unsigned long long dpp_u64(unsigned long long k) {
  int lo = (int)(unsigned int)k, hi = (int)(unsigned int)(k >> 32);
  lo = __builtin_amdgcn_update_dpp(lo, lo, CTRL, 0xf, 0xf, false);
  hi = __builtin_amdgcn_update_dpp(hi, hi, CTRL, 0xf, 0xf, false);
  return ((unsigned long long)(unsigned int)hi << 32) | (unsigned int)lo;
}

// 6-step wave(64) u64 max; result valid in lane 63. Requires full exec.
__device__ __forceinline__ unsigned long long wave_max_u64_dpp(unsigned long long k) {
  unsigned long long t;
  t = dpp_u64<0x111>(k); if (t > k) k = t;  // row_shr:1
  t = dpp_u64<0x112>(k); if (t > k) k = t;  // row_shr:2
  t = dpp_u64<0x114>(k); if (t > k) k = t;  // row_shr:4
  t = dpp_u64<0x118>(k); if (t > k) k = t;  // row_shr:8
  t = dpp_u64<0x142>(k); if (t > k) k = t;  // row_bcast15
  t = dpp_u64<0x143>(k); if (t > k) k = t;  // row_bcast31
  return k;
}

// ---------------------------------------------------------------------------
// FPS with bit-exact spatial pruning (replaces the r12 brute-force loop).
//   * Points counting-sorted into 64 spatial cells (4x4x4 over batch bbox);
//     groups = 64 consecutive POSITIONS (always full). Permutation affects
//     only speed: selection uses orig-index keys, so output is unchanged.
//   * Per step: each lane tests its group's bbox lower bound against the
//     group's cached max-dist (gmax). lb_safe = lb*0.999f < true distance of
//     every point in the group (fp32 rounding ~1e-7 << 1e-3 margin), so a
//     skipped group provably has min(dist,d)=dist for all its points and an
//     unchanged argmax key -> skip is bit-exact.
//   * Updated groups are striped across waves ((g&3)==wave); masks are
//     wave-uniform (computed from identical post-barrier gkey reads), so the
//     stripes are disjoint and the DPP reduce runs with full exec.
//   * gkey double-buffered by step parity + wave-0 copy-forward of skipped
//     groups -> ONE barrier per step. sp[pos].w (dist) write races with xyz
//     reads are benign (different dwords).
//   * Key = (distbits<<24)|(4095-orig)<<12|pos: max-reduce == argmax with
//     first-ORIGINAL-index tie-break (matches jnp.argmax exactly).
// Blocks >= 8: fused feature transpose (unchanged r12 logic, tile aliases sp).
// ---------------------------------------------------------------------------
__global__ __launch_bounds__(256) void fps_kernel(const float* __restrict__ xyz,
                                                  int* __restrict__ fps_idx,
                                                  float* __restrict__ nxyz,
                                                  float* __restrict__ out0,
                                                  const float* __restrict__ feature,
                                                  float* __restrict__ featT) {
  const int tid = threadIdx.x;
  __shared__ __align__(16) float4 sp[N_];          // 64 KB: xyz + dist in .w (pos-major)
  __shared__ unsigned short sidx[N_];              // pos -> original index
  __shared__ unsigned short spos[S_];              // selected positions
  __shared__ int si[S_];                           // selected original indices
  __shared__ float bbx0[64], bbx1[64], bby0[64], bby1[64], bbz0[64], bbz1[64];
  __shared__ unsigned long long gkey[2][64];       // per-group argmax key, dbuf
  __shared__ int hist[64];
  __shared__ float red[24];
  if (blockIdx.x >= 8) {
    // ---- fused transpose (r12-validated) ----
    const int blk = blockIdx.x - 8;
    const int b = blk >> 6, n0 = (blk & 63) * 64;
    float* tile = (float*)sp;  // 64*65 floats
#pragma unroll
    for (int i = 0; i < 16; i++) {
      int c = i * 4 + (tid >> 6), nl = tid & 63;
      tile[c * 65 + nl] = feature[((size_t)b * 64 + c) * N_ + n0 + nl];
    }
    __syncthreads();
#pragma unroll
    for (int i = 0; i < 16; i++) {
      int nl = i * 4 + (tid >> 6), c = tid & 63;
      featT[((size_t)b * N_ + n0 + nl) * 64 + c] = tile[c * 65 + nl];
    }
    return;
  }
  const int b = blockIdx.x;
  const int lane = tid & 63, wav = tid >> 6;
  const float* xb = xyz + (size_t)b * 3 * N_;
  const float4* xv = (const float4*)xb;
  float px[16], py[16], pz[16];
#pragma unroll
  for (int q = 0; q < 4; q++) {
    float4 X = xv[4 * tid + q];
    float4 Y = xv[1024 + 4 * tid + q];
    float4 Z = xv[2048 + 4 * tid + q];
    px[4 * q + 0] = X.x; px[4 * q + 1] = X.y; px[4 * q + 2] = X.z; px[4 * q + 3] = X.w;
    py[4 * q + 0] = Y.x; py[4 * q + 1] = Y.y; py[4 * q + 2] = Y.z; py[4 * q + 3] = Y.w;
    pz[4 * q + 0] = Z.x; pz[4 * q + 1] = Z.y; pz[4 * q + 2] = Z.z; pz[4 * q + 3] = Z.w;
  }
  // ---- batch bbox (for the spatial cells; quality affects speed only) ----
  float mnx = px[0], mxx = px[0], mny = py[0], mxy = py[0], mnz = pz[0], mxz = pz[0];
#pragma unroll
  for (int i = 1; i < 16; i++) {
    mnx = fminf(mnx, px[i]); mxx = fmaxf(mxx, px[i]);
    mny = fminf(mny, py[i]); mxy = fmaxf(mxy, py[i]);
    mnz = fminf(mnz, pz[i]); mxz = fmaxf(mxz, pz[i]);
  }
#pragma unroll
  for (int off = 32; off >= 1; off >>= 1) {
    mnx = fminf(mnx, __shfl_xor(mnx, off)); mxx = fmaxf(mxx, __shfl_xor(mxx, off));
    mny = fminf(mny, __shfl_xor(mny, off)); mxy = fmaxf(mxy, __shfl_xor(mxy, off));
    mnz = fminf(mnz, __shfl_xor(mnz, off)); mxz = fmaxf(mxz, __shfl_xor(mxz, off));
  }
  if (lane == 0) {
    red[wav * 6 + 0] = mnx; red[wav * 6 + 1] = mxx;
    red[wav * 6 + 2] = mny; red[wav * 6 + 3] = mxy;
    red[wav * 6 + 4] = mnz; red[wav * 6 + 5] = mxz;
  }
  if (tid < 64) hist[tid] = 0;
  __syncthreads();
  const float Bx0 = fminf(fminf(red[0], red[6]), fminf(red[12], red[18]));
  const float Bx1 = fmaxf(fmaxf(red[1], red[7]), fmaxf(red[13], red[19]));
  const float By0 = fminf(fminf(red[2], red[8]), fminf(red[14], red[20]));
  const float By1 = fmaxf(fmaxf(red[3], red[9]), fmaxf(red[15], red[21]));
  const float Bz0 = fminf(fminf(red[4], red[10]), fminf(red[16], red[22]));
  const float Bz1 = fmaxf(fmaxf(red[5], red[11]), fmaxf(red[17], red[23]));
  const float sxs = 4.0f / fmaxf(Bx1 - Bx0, 1e-20f);
  const float sys = 4.0f / fmaxf(By1 - By0, 1e-20f);
  const float szs = 4.0f / fmaxf(Bz1 - Bz0, 1e-20f);
  int cid[16];
#pragma unroll
  for (int i = 0; i < 16; i++) {
    int ix = min(3, (int)((px[i] - Bx0) * sxs));
    int iy = min(3, (int)((py[i] - By0) * sys));
    int iz = min(3, (int)((pz[i] - Bz0) * szs));
    cid[i] = (ix << 4) | (iy << 2) | iz;
    atomicAdd(&hist[cid[i]], 1);
  }
  __syncthreads();
  if (tid == 0) {
    int acc = 0;
    for (int g = 0; g < 64; g++) { int h = hist[g]; hist[g] = acc; acc += h; }
  }
  __syncthreads();
#pragma unroll
  for (int i = 0; i < 16; i++) {
    int pos = atomicAdd(&hist[cid[i]], 1);
    sp[pos] = make_float4(px[i], py[i], pz[i], 1e10f);  // dist init matches reference
    int orig = 16 * tid + i;
    sidx[pos] = (unsigned short)orig;
    if (orig == 0) { spos[0] = (unsigned short)pos; si[0] = 0; }
  }
  __syncthreads();
  // ---- static per-group (64 positions) bboxes ----
  if (tid < 64) {
    float4 P = sp[tid * 64];
    float a0 = P.x, a1 = P.x, b0 = P.y, b1 = P.y, c0 = P.z, c1 = P.z;
    for (int j = 1; j < 64; j++) {
      P = sp[tid * 64 + j];
      a0 = fminf(a0, P.x); a1 = fmaxf(a1, P.x);
      b0 = fminf(b0, P.y); b1 = fmaxf(b1, P.y);
      c0 = fminf(c0, P.z); c1 = fmaxf(c1, P.z);
    }
    bbx0[tid] = a0; bbx1[tid] = a1;
    bby0[tid] = b0; bby1[tid] = b1;
    bbz0[tid] = c0; bbz1[tid] = c1;
  }
  __syncthreads();
  const float gx0 = bbx0[lane], gx1 = bbx1[lane];
  const float gy0 = bby0[lane], gy1 = bby1[lane];
  const float gz0 = bbz0[lane], gz1 = bbz1[lane];
  unsigned long long gq = ((unsigned long long)__float_as_uint(1e10f)) << 24;
  float4 c0v = sp[spos[0]];
  float cx = c0v.x, cy = c0v.y, cz = c0v.z;
  const unsigned long long stripe = 0x1111111111111111ULL << wav;
  for (int s = 1; s < S_; s++) {
    const int p = s & 1;
    // conservative lower bound of d(c, any point in group `lane`)
    float tx = fmaxf(fmaxf(__fsub_rn(gx0, cx), __fsub_rn(cx, gx1)), 0.f);
    float ty = fmaxf(fmaxf(__fsub_rn(gy0, cy), __fsub_rn(cy, gy1)), 0.f);
    float tz = fmaxf(fmaxf(__fsub_rn(gz0, cz), __fsub_rn(cz, gz1)), 0.f);
    float lb = tx * tx + ty * ty + tz * tz;
    float gmax = __uint_as_float((unsigned int)(gq >> 24));
    bool upd = (lb * 0.999f) < gmax;  // margin >> fp32 rounding -> skip is exact
    unsigned long long mask = __ballot(upd);   // identical in all waves
    if (wav == 0 && !upd) gkey[p][lane] = gq;  // copy-forward skipped groups
    unsigned long long m = mask & stripe;      // this wave's disjoint share
    while (m) {  // wave-uniform loop: full exec inside (DPP-safe)
      int g = __ffsll(m) - 1; m &= m - 1;
      int pp = g * 64 + lane;
      float4 P = sp[pp];
      unsigned int oi = sidx[pp];
      // identical arithmetic/op-order to all validated rounds
      float dx = __fsub_rn(P.x, cx), dy = __fsub_rn(P.y, cy), dz = __fsub_rn(P.z, cz);
      float d = __fadd_rn(__fadd_rn(__fmul_rn(dx, dx), __fmul_rn(dy, dy)), __fmul_rn(dz, dz));
      float nd = fminf(P.w, d);
      sp[pp].w = nd;
      unsigned long long k = ((unsigned long long)__float_as_uint(nd) << 24) |
                             ((unsigned long long)(4095u - oi) << 12) | (unsigned int)pp;
      k = wave_max_u64_dpp(k);
      if (lane == 63) gkey[p][g] = k;
    }
    __syncthreads();
    // scan all 64 group keys (every wave redundantly; refreshes gq cache)
    unsigned long long kq = gkey[p][lane];
    gq = kq;
    unsigned long long kk = wave_max_u64_dpp(kq);
    unsigned int lo = (unsigned int)__builtin_amdgcn_readlane((int)(unsigned int)kk, 63);
    unsigned int hi = (unsigned int)__builtin_amdgcn_readlane((int)(unsigned int)(kk >> 32), 63);
    unsigned long long kwin = ((unsigned long long)hi << 32) | lo;
    int pos = (int)(kwin & 0xfffull);
    if (tid == 0) {
      si[s] = 4095 - (int)((kwin >> 12) & 0xfffull);
      spos[s] = (unsigned short)pos;
    }
    float4 C = sp[pos];  // .w race with next step's writes is benign (xyz only)
    cx = C.x; cy = C.y; cz = C.z;
  }
  __syncthreads();
  for (int e = tid; e < S_; e += 256) {
    int n = si[e];
    float4 c = sp[spos[e]];
    fps_idx[b * S_ + e] = n;
    nxyz[(size_t)(b * S_ + e) * 3 + 0] = c.x;
    nxyz[(size_t)(b * S_ + e) * 3 + 1] = c.y;
    nxyz[(size_t)(b * S_ + e) * 3 + 2] = c.z;
    out0[(size_t)b * 3 * S_ + e] = c.x;
    out0[(size_t)b * 3 * S_ + S_ + e] = c.y;
    out0[(size_t)b * 3 * S_ + 2 * S_ + e] = c.z;
  }
}

// ---------------------------------------------------------------------------
// kNN (r12-validated, unchanged). Blocks >= 8192: fused anchor gather.
// ---------------------------------------------------------------------------
__global__ __launch_bounds__(256) void knn_kernel(const float* __restrict__ xyz,
                                                  const float* __restrict__ nxyz,
                                                  int* __restrict__ knn,
                                                  const float* __restrict__ featT,
                                                  const int* __restrict__ fps_i,
                                                  float* __restrict__ nfeat) {
  const int bs = blockIdx.x, tid = threadIdx.x;
  if (bs >= 8192) {
    int e = (bs - 8192) * 256 + tid;
    int bsx = e >> 6, c = e & 63;
    int bq = bsx >> 10;
    int n = fps_i[bsx];
    nfeat[e] = featT[((size_t)bq * N_ + n) * 64 + c];
    return;
  }
  const int b = bs >> 10;
  const float* xb = xyz + (size_t)b * 3 * N_;
  const float cx = nxyz[(size_t)bs * 3], cy = nxyz[(size_t)bs * 3 + 1], cz = nxyz[(size_t)bs * 3 + 2];
  const float cn = __fadd_rn(__fadd_rn(__fmul_rn(cx, cx), __fmul_rn(cy, cy)), __fmul_rn(cz, cz));
  float d[16];
#pragma unroll
  for (int i = 0; i < 16; i++) {
    int n = i * 256 + tid;
    float px = xb[n], py = xb[N_ + n], pz = xb[2 * N_ + n];
    float pn = __fadd_rn(__fadd_rn(__fmul_rn(px, px), __fmul_rn(py, py)), __fmul_rn(pz, pz));
    float dot = __fadd_rn(__fadd_rn(__fmul_rn(cx, px), __fmul_rn(cy, py)), __fmul_rn(cz, pz));
    d[i] = __fsub_rn(__fadd_rn(cn, pn), __fmul_rn(2.0f, dot));
  }
  float mv = FLT_MAX;
  int mi = tid;
#pragma unroll
  for (int i = 0; i < 16; i++)
    if (d[i] < mv) { mv = d[i]; mi = i * 256 + tid; }
  __shared__ unsigned long long keyp[2][4];
  __shared__ int skk[K_];
  const int wav = tid >> 6, lane = tid & 63;
  for (int j = 0; j < K_; j++) {
    unsigned int u = __float_as_uint(mv);
    u ^= ((unsigned int)((int)u >> 31) | 0x80000000u);
    unsigned long long key = ((unsigned long long)u << 32) | (unsigned int)mi;
#pragma unroll
    for (int off = 32; off >= 1; off >>= 1) {
      unsigned long long ok = __shfl_xor(key, off);
      if (ok < key) key = ok;
    }
    if (lane == 0) keyp[j & 1][wav] = key;
    __syncthreads();
    unsigned long long kmin = keyp[j & 1][0];
#pragma unroll
    for (int w = 1; w < 4; w++) {
      unsigned long long k2 = keyp[j & 1][w];
      if (k2 < kmin) kmin = k2;
    }
    int g = (int)(kmin & 0xffffffffull);
    if (tid == 0) skk[j] = g;
    if ((g & 255) == tid) {
      int sl = g >> 8;
#pragma unroll
      for (int i = 0; i < 16; i++)
        if (i == sl) d[i] = FLT_MAX;
      mv = FLT_MAX; mi = tid;
#pragma unroll
      for (int i = 0; i < 16; i++)
        if (d[i] < mv) { mv = d[i]; mi = i * 256 + tid; }
    }
  }
  __syncthreads();
  if (tid < K_) knn[(size_t)bs * K_ + tid] = skk[tid];
}

// ===========================================================================
// ============ FALLBACK kernels — used when ws is small =====================
// ===========================================================================
__global__ __launch_bounds__(256) void gather_nf(const float* __restrict__ feature,
                                                 const int* __restrict__ fps_i,
                                                 float* __restrict__ nfeat) {
  int e = blockIdx.x * 256 + threadIdx.x;
  int b = e >> 16, rem = e & 65535;
  int s = rem >> 6, c = rem & 63;
  int n = fps_i[b * S_ + s];
  nfeat[e] = feature[((size_t)b * 64 + c) * N_ + n];
}

__global__ __launch_bounds__(256) void std_partial(const float* __restrict__ feature,
                                                   const float* __restrict__ xyz,
                                                   const float* __restrict__ nxyz,
                                                   const float* __restrict__ nfeat,
                                                   const int* __restrict__ knn,
                                                   float* __restrict__ outp) {
  const int blk = blockIdx.x, tid = threadIdx.x;
  const int b = blk >> 6, chunk = blk & 63;
  float s = 0.f, q = 0.f;
  for (int e = tid; e < 16 * K_ * 67; e += 256) {
    int so = e / (K_ * 67);
    int rem = e - so * (K_ * 67);
    int kk = rem / 67;
    int c = rem - kk * 67;
    int bs = b * S_ + chunk * 16 + so;
    int n = knn[(size_t)bs * K_ + kk];
    float raw = (c < 64) ? feature[((size_t)b * 64 + c) * N_ + n]
                         : xyz[((size_t)b * 3 + (c - 64)) * N_ + n];
    float anc = (c < 64) ? nfeat[(size_t)bs * 64 + c]
                         : nxyz[(size_t)bs * 3 + (c - 64)];
    float dd = raw - anc;
    s += dd; q += dd * dd;
  }
#pragma unroll
  for (int off = 32; off >= 1; off >>= 1) { s += __shfl_xor(s, off); q += __shfl_xor(q, off); }
  __shared__ float rs[4], rq[4];
  if ((tid & 63) == 0) { rs[tid >> 6] = s; rq[tid >> 6] = q; }
  __syncthreads();
  if (tid == 0) {
    outp[blk * 2] = rs[0] + rs[1] + rs[2] + rs[3];
    outp[blk * 2 + 1] = rq[0] + rq[1] + rq[2] + rq[3];
  }
}

__global__ void std_final(const float* __restrict__ part, float* __restrict__ invstd) {
  int b = threadIdx.x;
  if (b < B_) {
    double s = 0.0, q = 0.0;
    for (int i = 0; i < 64; i++) {
      s += (double)part[(b * 64 + i) * 2];
      q += (double)part[(b * 64 + i) * 2 + 1];
    }
    const double n = (double)(S_ * K_ * 67);
    double var = (q - s * s / n) / (n - 1.0);
    invstd[b] = (float)(1.0 / (sqrt(var) + 1e-5));
  }
}

template <int MODE>
__global__ __launch_bounds__(256, 2) void mlp_kernel(
    const float* __restrict__ feature, const float* __restrict__ xyz,
    const float* __restrict__ nxyz, const float* __restrict__ nfeat,
    const int* __restrict__ knn, const float* __restrict__ invstd,
    const float* __restrict__ alpha, const float* __restrict__ beta,
    const float* __restrict__ w_tr, const float* __restrict__ b_tr,
    const float* __restrict__ w1, const float* __restrict__ b1,
    const float* __restrict__ w2, const float* __restrict__ b2,
    const float* __restrict__ bn_tr, const float* __restrict__ bn_1,
    float* __restrict__ bnpart, float* __restrict__ out1) {
  __shared__ __align__(16) float pool[15556];
  float* Wt = pool;
  float* xin = pool + 8516;
  float* ub = xin;
  float* tb = pool + 8516 + 4192;
  float* part = pool + 8516 + 4192 + 2304;
  int* sknn = (int*)(part + 512);
  const int bs = blockIdx.x, tid = threadIdx.x;
  const int b = bs >> 10, s = bs & 1023;
  if (tid < K_) sknn[tid] = knn[(size_t)bs * K_ + tid];
  for (int e = tid; e < 64 * 131; e += 256) {
    int o = e / 131, c = e - o * 131;
    Wt[c * 65 + o] = w_tr[e];
  }
  __syncthreads();
  const float inv = invstd[b];
  for (int e = tid; e < CIN_ * K_; e += 256) {
    int c = e >> 5, kk = e & 31;
    float v;
    if (c < 67) {
      int n = sknn[kk];
      float raw = (c < 64) ? feature[((size_t)b * 64 + c) * N_ + n]
                           : xyz[((size_t)b * 3 + (c - 64)) * N_ + n];
      float anc = (c < 64) ? nfeat[(size_t)bs * 64 + c]
                           : nxyz[(size_t)bs * 3 + (c - 64)];
      v = alpha[c] * ((raw - anc) * inv) + beta[c];
    } else {
      v = nfeat[(size_t)bs * 64 + (c - 67)];
    }
    xin[e] = v;
  }
  __syncthreads();
  const int o = tid & 63, kkb = (tid >> 6) * 8;
  float acc[8];
  {
    float bv = b_tr[o];
#pragma unroll
    for (int j = 0; j < 8; j++) acc[j] = bv;
  }
  for (int c = 0; c < CIN_; c++) {
    float w = Wt[c * 65 + o];
    const float4 xa = *(const float4*)(xin + c * 32 + kkb);
    const float4 xb4 = *(const float4*)(xin + c * 32 + kkb + 4);
    acc[0] += w * xa.x; acc[1] += w * xa.y; acc[2] += w * xa.z; acc[3] += w * xa.w;
    acc[4] += w * xb4.x; acc[5] += w * xb4.y; acc[6] += w * xb4.z; acc[7] += w * xb4.w;
  }
  if (MODE == 0) {
    float s8 = 0.f, q8 = 0.f;
#pragma unroll
    for (int j = 0; j < 8; j++) { s8 += acc[j]; q8 += acc[j] * acc[j]; }
    part[(tid >> 6) * 64 + o] = s8;
    part[256 + (tid >> 6) * 64 + o] = q8;
    __syncthreads();
    if (tid < 64) {
      float ss = 0.f, qq = 0.f;
      for (int g = 0; g < 4; g++) { ss += part[g * 64 + tid]; qq += part[256 + g * 64 + tid]; }
      bnpart[(size_t)bs * 128 + tid] = ss;
      bnpart[(size_t)bs * 128 + 64 + tid] = qq;
    }
    return;
  }
  float tv[8];
  {
    float sc = bn_tr[o], sh = bn_tr[64 + o];
#pragma unroll
    for (int j = 0; j < 8; j++) {
      tv[j] = fmaxf(fmaf(sc, acc[j], sh), 0.f);
      tb[o * 36 + kkb + j] = tv[j];
    }
  }
  __syncthreads();
  for (int e = tid; e < 64 * 64; e += 256) {
    int oo = e >> 6, c = e & 63;
    Wt[c * 65 + oo] = w1[e];
  }
  __syncthreads();
  float acc2[8];
  {
    float bv = b1[o];
#pragma unroll
    for (int j = 0; j < 8; j++) acc2[j] = bv;
  }
  for (int c = 0; c < 64; c++) {
    float w = Wt[c * 65 + o];
    const float4 ta = *(const float4*)(tb + c * 36 + kkb);
    const float4 ta2 = *(const float4*)(tb + c * 36 + kkb + 4);
    acc2[0] += w * ta.x; acc2[1] += w * ta.y; acc2[2] += w * ta.z; acc2[3] += w * ta.w;
    acc2[4] += w * ta2.x; acc2[5] += w * ta2.y; acc2[6] += w * ta2.z; acc2[7] += w * ta2.w;
  }
  if (MODE == 1) {
    float s8 = 0.f, q8 = 0.f;
#pragma unroll
    for (int j = 0; j < 8; j++) { s8 += acc2[j]; q8 += acc2[j] * acc2[j]; }
    part[(tid >> 6) * 64 + o] = s8;
    part[256 + (tid >> 6) * 64 + o] = q8;
    __syncthreads();
    if (tid < 64) {
      float ss = 0.f, qq = 0.f;
      for (int g = 0; g < 4; g++) { ss += part[g * 64 + tid]; qq += part[256 + g * 64 + tid]; }
      bnpart[(size_t)bs * 128 + tid] = ss;
      bnpart[(size_t)bs * 128 + 64 + tid] = qq;
    }
    return;
  }
  {
    float sc = bn_1[o], sh = bn_1[64 + o];
#pragma unroll
    for (int j = 0; j < 8; j++) ub[o * 36 + kkb + j] = fmaxf(fmaf(sc, acc2[j], sh), 0.f);
  }
  __syncthreads();
  for (int e = tid; e < 64 * 64; e += 256) {
    int oo = e >> 6, c = e & 63;
    Wt[c * 65 + oo] = w2[e];
  }
  __syncthreads();
  float acc3[8];
  {
    float bv = b2[o];
#pragma unroll
    for (int j = 0; j < 8; j++) acc3[j] = bv;
  }
  for (int c = 0; c < 64; c++) {
    float w = Wt[c * 65 + o];
    const float4 ua = *(const float4*)(ub + c * 36 + kkb);
    const float4 ua2 = *(const float4*)(ub + c * 36 + kkb + 4);
    acc3[0] += w * ua.x; acc3[1] += w * ua.y; acc3[2] += w * ua.z; acc3[3] += w * ua.w;
    acc3[4] += w * ua2.x; acc3[5] += w * ua2.y; acc3[6] += w * ua2.z; acc3[7] += w * ua2.w;
  }
  float m = 0.f;
#pragma unroll
  for (int j = 0; j < 8; j++) m = fmaxf(m, fmaxf(acc3[j] + tv[j], 0.f));
  part[(tid >> 6) * 64 + o] = m;
  __syncthreads();
  if (tid < 64) {
    float mm = part[tid];
    for (int g = 1; g < 4; g++) mm = fmaxf(mm, part[g * 64 + tid]);
    out1[((size_t)b * 64 + tid) * S_ + s] = mm;
  }
}

// ---------------------------------------------------------------------------
// BN finalize (shared by both paths).
// ---------------------------------------------------------------------------
__global__ __launch_bounds__(256) void bn_finalize(const float* __restrict__ part,
                                                   const float* __restrict__ g,
                                                   const float* __restrict__ be,
                                                   float* __restrict__ bnout) {
  const int ch = blockIdx.x, tid = threadIdx.x;
  double s = 0.0, q = 0.0;
  for (int i = tid; i < B_ * S_; i += 256) {
    s += (double)part[(size_t)i * 128 + ch];
    q += (double)part[(size_t)i * 128 + 64 + ch];
  }
#pragma unroll
  for (int off = 32; off >= 1; off >>= 1) { s += __shfl_xor(s, off); q += __shfl_xor(q, off); }
  __shared__ double ls[4], lq[4];
  if ((tid & 63) == 0) { ls[tid >> 6] = s; lq[tid >> 6] = q; }
  __syncthreads();
  if (tid == 0) {
    double Ssum = ls[0] + ls[1] + ls[2] + ls[3];
    double Qsum = lq[0] + lq[1] + lq[2] + lq[3];
    const double n = (double)(B_ * S_ * K_);
    double mu = Ssum / n;
    double var = Qsum / n - mu * mu;
    double sc = (double)g[ch] / sqrt(var + 1e-5);
    bnout[ch] = (float)sc;
    bnout[64 + ch] = (float)((double)be[ch] - mu * sc);
  }
}

// ===========================================================================
// ================== CACHE-PATH kernels (large workspace) ===================
// ===========================================================================
__global__ __launch_bounds__(256) void prep_kernel(const float* __restrict__ featT,
                                                   const float* __restrict__ xyz,
                                                   const float* __restrict__ nxyz,
                                                   const float* __restrict__ nfeat,
                                                   const int* __restrict__ knn,
                                                   float* __restrict__ dcache,
                                                   float* __restrict__ outp) {
  const int blk = blockIdx.x, tid = threadIdx.x;
  __shared__ int sk[32];
  float s = 0.f, q = 0.f;
  const int c = tid & 63, qd = tid >> 6;
  for (int g = 0; g < 8; g++) {
    const int bs = blk * 8 + g, b = bs >> 10;
    if (tid < 32) sk[tid] = knn[(size_t)bs * K_ + tid];
    __syncthreads();
    float anc = nfeat[(size_t)bs * 64 + c];
#pragma unroll
    for (int it = 0; it < 8; it++) {
      int kk = it * 4 + qd;
      int n = sk[kk];
      float dd = featT[((size_t)b * N_ + n) * 64 + c] - anc;
      s += dd; q += dd * dd;
      dcache[((size_t)bs * 32 + kk) * 68 + c] = dd;
    }
    if (tid < 96) {
      int c3 = tid >> 5, kk = tid & 31;
      int n = sk[kk];
      float dd = xyz[((size_t)b * 3 + c3) * N_ + n] - nxyz[(size_t)bs * 3 + c3];
      s += dd; q += dd * dd;
      dcache[((size_t)bs * 32 + kk) * 68 + 64 + c3] = dd;
    }
    __syncthreads();
  }
#pragma unroll
  for (int off = 32; off >= 1; off >>= 1) { s += __shfl_xor(s, off); q += __shfl_xor(q, off); }
  __shared__ float rs[4], rq[4];
  if ((tid & 63) == 0) { rs[tid >> 6] = s; rq[tid >> 6] = q; }
  __syncthreads();
  if (tid == 0) {
    outp[blk * 2] = rs[0] + rs[1] + rs[2] + rs[3];
    outp[blk * 2 + 1] = rq[0] + rq[1] + rq[2] + rq[3];
  }
}

__global__ void std_final_c(const float* __restrict__ part, float* __restrict__ invstd) {
  int b = threadIdx.x;
  if (b < B_) {
    double s = 0.0, q = 0.0;
    for (int i = 0; i < 128; i++) {
      s += (double)part[(b * 128 + i) * 2];
      q += (double)part[(b * 128 + i) * 2 + 1];
    }
    const double n = (double)(S_ * K_ * 67);
    double var = (q - s * s / n) / (n - 1.0);
    invstd[b] = (float)(1.0 / (sqrt(var) + 1e-5));
  }
}

__global__ __launch_bounds__(256, 2) void mlp0c(
    const float* __restrict__ dcache, const float* __restrict__ nfeat,
    const float* __restrict__ invstd,
    const float* __restrict__ alpha, const float* __restrict__ beta,
    const float* __restrict__ w_tr, const float* __restrict__ b_tr,
    float* __restrict__ bnpart, float* __restrict__ tcache) {
  __shared__ __align__(16) float pool[13220];
  float* Wt = pool;
  float* xin = pool + 8516;
  float* part = pool + 8516 + 4192;
  const int bs = blockIdx.x, tid = threadIdx.x;
  const int b = bs >> 10;
  for (int e = tid; e < 64 * 131; e += 256) {
    int o = e / 131, c = e - o * 131;
    Wt[c * 65 + o] = w_tr[e];
  }
  const float inv = invstd[b];
  {
    const int c = tid & 63, qd = tid >> 6;
    float al = alpha[c], bev = beta[c];
#pragma unroll
    for (int it = 0; it < 8; it++) {
      int kk = it * 4 + qd;
      xin[c * 32 + kk] = al * (dcache[((size_t)bs * 32 + kk) * 68 + c] * inv) + bev;
    }
    if (tid < 96) {
      int c3 = 64 + (tid >> 5), kk = tid & 31;
      xin[c3 * 32 + kk] =
          alpha[c3] * (dcache[((size_t)bs * 32 + kk) * 68 + c3] * inv) + beta[c3];
    }
    for (int e = tid; e < 2048; e += 256) {
      int cc = 67 + (e >> 5), kk = e & 31;
      xin[cc * 32 + kk] = nfeat[(size_t)bs * 64 + (e >> 5)];
    }
  }
  __syncthreads();
  const int o = tid & 63, kkb = (tid >> 6) * 8;
  float acc[8];
  {
    float bv = b_tr[o];
#pragma unroll
    for (int j = 0; j < 8; j++) acc[j] = bv;
  }
  for (int c = 0; c < CIN_; c++) {
    float w = Wt[c * 65 + o];
    const float4 xa = *(const float4*)(xin + c * 32 + kkb);
    const float4 xb4 = *(const float4*)(xin + c * 32 + kkb + 4);
    acc[0] += w * xa.x; acc[1] += w * xa.y; acc[2] += w * xa.z; acc[3] += w * xa.w;
    acc[4] += w * xb4.x; acc[5] += w * xb4.y; acc[6] += w * xb4.z; acc[7] += w * xb4.w;
  }
  {
    float4* tp = (float4*)(tcache + ((size_t)bs * 64 + o) * 32 + kkb);
    tp[0] = make_float4(acc[0], acc[1], acc[2], acc[3]);
    tp[1] = make_float4(acc[4], acc[5], acc[6], acc[7]);
  }
  float s8 = 0.f, q8 = 0.f;
#pragma unroll
  for (int j = 0; j < 8; j++) { s8 += acc[j]; q8 += acc[j] * acc[j]; }
  part[(tid >> 6) * 64 + o] = s8;
  part[256 + (tid >> 6) * 64 + o] = q8;
  __syncthreads();
  if (tid < 64) {
    float ss = 0.f, qq = 0.f;
    for (int g = 0; g < 4; g++) { ss += part[g * 64 + tid]; qq += part[256 + g * 64 + tid]; }
    bnpart[(size_t)bs * 128 + tid] = ss;
    bnpart[(size_t)bs * 128 + 64 + tid] = qq;
  }
}

__global__ __launch_bounds__(256, 3) void mlp1c(
    const float* __restrict__ tcache, const float* __restrict__ bn_tr,
    const float* __restrict__ w1, const float* __restrict__ b1,
    float* __restrict__ bnpart, float* __restrict__ ucache) {
  __shared__ __align__(16) float pool[6976];
  float* Wt = pool;
  float* tb = pool + 4160;
  float* part = pool + 4160 + 2304;
  const int bs = blockIdx.x, tid = threadIdx.x;
  const int o = tid & 63, kkb = (tid >> 6) * 8;
  for (int e = tid; e < 64 * 64; e += 256) {
    int oo = e >> 6, c = e & 63;
    Wt[c * 65 + oo] = w1[e];
  }
  float t[8];
  {
    const float4* tp = (const float4*)(tcache + ((size_t)bs * 64 + o) * 32 + kkb);
    float4 a = tp[0], b4 = tp[1];
    t[0] = a.x; t[1] = a.y; t[2] = a.z; t[3] = a.w;
    t[4] = b4.x; t[5] = b4.y; t[6] = b4.z; t[7] = b4.w;
  }
  {
    float sc = bn_tr[o], sh = bn_tr[64 + o];
#pragma unroll
    for (int j = 0; j < 8; j++) tb[o * 36 + kkb + j] = fmaxf(fmaf(sc, t[j], sh), 0.f);
  }
  __syncthreads();
  float acc2[8];
  {
    float bv = b1[o];
#pragma unroll
    for (int j = 0; j < 8; j++) acc2[j] = bv;
  }
  for (int c = 0; c < 64; c++) {
    float w = Wt[c * 65 + o];
    const float4 ta = *(const float4*)(tb + c * 36 + kkb);
    const float4 ta2 = *(const float4*)(tb + c * 36 + kkb + 4);
    acc2[0] += w * ta.x; acc2[1] += w * ta.y; acc2[2] += w * ta.z; acc2[3] += w * ta.w;
    acc2[4] += w * ta2.x; acc2[5] += w * ta2.y; acc2[6] += w * ta2.z; acc2[7] += w * ta2.w;
  }
  {
    float4* up = (float4*)(ucache + ((size_t)bs * 64 + o) * 32 + kkb);
    up[0] = make_float4(acc2[0], acc2[1], acc2[2], acc2[3]);
    up[1] = make_float4(acc2[4], acc2[5], acc2[6], acc2[7]);
  }
  float s8 = 0.f, q8 = 0.f;
#pragma unroll
  for (int j = 0; j < 8; j++) { s8 += acc2[j]; q8 += acc2[j] * acc2[j]; }
  part[(tid >> 6) * 64 + o] = s8;
  part[256 + (tid >> 6) * 64 + o] = q8;
  __syncthreads();
  if (tid < 64) {
    float ss = 0.f, qq = 0.f;
    for (int g = 0; g < 4; g++) { ss += part[g * 64 + tid]; qq += part[256 + g * 64 + tid]; }
    bnpart[(size_t)bs * 128 + tid] = ss;
    bnpart[(size_t)bs * 128 + 64 + tid] = qq;
  }
}

__global__ __launch_bounds__(256, 3) void mlp2c(
    const float* __restrict__ tcache, const float* __restrict__ ucache,
    const float* __restrict__ bn_tr, const float* __restrict__ bn_1,
    const float* __restrict__ w2, const float* __restrict__ b2,
    float* __restrict__ out1) {
  __shared__ __align__(16) float pool[6976];
  float* Wt = pool;
  float* ub = pool + 4160;
  float* part = pool + 4160 + 2304;
  const int bs = blockIdx.x, tid = threadIdx.x;
  const int b = bs >> 10, s = bs & 1023;
  const int o = tid & 63, kkb = (tid >> 6) * 8;
  for (int e = tid; e < 64 * 64; e += 256) {
    int oo = e >> 6, c = e & 63;
    Wt[c * 65 + oo] = w2[e];
  }
  {
    const float4* up = (const float4*)(ucache + ((size_t)bs * 64 + o) * 32 + kkb);
    float4 a = up[0], b4 = up[1];
    float u[8] = {a.x, a.y, a.z, a.w, b4.x, b4.y, b4.z, b4.w};
    float sc = bn_1[o], sh = bn_1[64 + o];
#pragma unroll
    for (int j = 0; j < 8; j++) ub[o * 36 + kkb + j] = fmaxf(fmaf(sc, u[j], sh), 0.f);
  }
  __syncthreads();
  float acc3[8];
  {
    float bv = b2[o];
#pragma unroll
    for (int j = 0; j < 8; j++) acc3[j] = bv;
  }
  for (int c = 0; c < 64; c++) {
    float w = Wt[c * 65 + o];
    const float4 ua = *(const float4*)(ub + c * 36 + kkb);
    const float4 ua2 = *(const float4*)(ub + c * 36 + kkb + 4);
    acc3[0] += w * ua.x; acc3[1] += w * ua.y; acc3[2] += w * ua.z; acc3[3] += w * ua.w;
    acc3[4] += w * ua2.x; acc3[5] += w * ua2.y; acc3[6] += w * ua2.z; acc3[7] += w * ua2.w;
  }
  float tv[8];
  {
    const float4* tp = (const float4*)(tcache + ((size_t)bs * 64 + o) * 32 + kkb);
    float4 a = tp[0], b4 = tp[1];
    float t[8] = {a.x, a.y, a.z, a.w, b4.x, b4.y, b4.z, b4.w};
    float sc = bn_tr[o], sh = bn_tr[64 + o];
#pragma unroll
    for (int j = 0; j < 8; j++) tv[j] = fmaxf(fmaf(sc, t[j], sh), 0.f);
  }
  float m = 0.f;
#pragma unroll
  for (int j = 0; j < 8; j++) m = fmaxf(m, fmaxf(acc3[j] + tv[j], 0.f));
  part[(tid >> 6) * 64 + o] = m;
  __syncthreads();
  if (tid < 64) {
    float mm = part[tid];
    for (int g = 1; g < 4; g++) mm = fmaxf(mm, part[g * 64 + tid]);
    out1[((size_t)b * 64 + tid) * S_ + s] = mm;
  }
}

// ---------------------------------------------------------------------------
extern "C" void kernel_launch(void* const* d_in, const int* in_sizes, int n_in,
                              void* d_out, int out_size, void* d_ws, size_t ws_size,
                              hipStream_t stream) {
  const float* xyz = (const float*)d_in[0];
  const float* feature = (const float*)d_in[1];
  const float* alpha = (const float*)d_in[2];
  const float* beta = (const float*)d_in[3];
  const float* w_tr = (const float*)d_in[4];
  const float* b_tr = (const float*)d_in[5];
  const float* g_tr = (const float*)d_in[6];
  const float* be_tr = (const float*)d_in[7];
  const float* w1 = (const float*)d_in[8];
  const float* b1 = (const float*)d_in[9];
  const float* g1 = (const float*)d_in[10];
  const float* be1 = (const float*)d_in[11];
  const float* w2 = (const float*)d_in[12];
  const float* b2 = (const float*)d_in[13];

  char* ws = (char*)d_ws;
  int* fps_i = (int*)(ws);                      // 32768 B
  float* nxyz = (float*)(ws + 32768);           // 98304 B
  float* nfeat = (float*)(ws + 131072);         // 2097152 B
  int* knn = (int*)(ws + 2228224);              // 1048576 B
  float* stdpart = (float*)(ws + 3276800);      // 4096 B (fallback)
  float* invstd = (float*)(ws + 3280896);       // 64 B
  float* bn_tr = (float*)(ws + 3280960);        // 512 B
  float* bn_1 = (float*)(ws + 3281472);         // 512 B
  float* bnpart = (float*)(ws + 3281984);       // 4194304 B -> end 7476288
  float* featT = (float*)(ws + 7476288);        // 8388608 B
  float* dcache = (float*)(ws + 15864896);      // 71303168 B
  float* tcache = (float*)(ws + 87168064);      // 67108864 B
  float* ucache = (float*)(ws + 154276928);     // 67108864 B
  float* stdpart_c = (float*)(ws + 221385792);  // 8192 B -> total 221393984

  float* out0 = (float*)d_out;
  float* out1 = out0 + B_ * 3 * S_;

  const bool big = (ws_size >= 221393984ull);

  if (big) {
    fps_kernel<<<8 + 512, 256, 0, stream>>>(xyz, fps_i, nxyz, out0, feature, featT);
    knn_kernel<<<8192 + 2048, 256, 0, stream>>>(xyz, nxyz, knn, featT, fps_i, nfeat);
    prep_kernel<<<1024, 256, 0, stream>>>(featT, xyz, nxyz, nfeat, knn, dcache, stdpart_c);
    std_final_c<<<1, 64, 0, stream>>>(stdpart_c, invstd);
    mlp0c<<<B_ * S_, 256, 0, stream>>>(dcache, nfeat, invstd, alpha, beta, w_tr, b_tr,
                                       bnpart, tcache);
    bn_finalize<<<64, 256, 0, stream>>>(bnpart, g_tr, be_tr, bn_tr);
    mlp1c<<<B_ * S_, 256, 0, stream>>>(tcache, bn_tr, w1, b1, bnpart, ucache);
    bn_finalize<<<64, 256, 0, stream>>>(bnpart, g1, be1, bn_1);
    mlp2c<<<B_ * S_, 256, 0, stream>>>(tcache, ucache, bn_tr, bn_1, w2, b2, out1);
  } else {
    fps_kernel<<<8, 256, 0, stream>>>(xyz, fps_i, nxyz, out0, feature, featT);
    gather_nf<<<(B_ * S_ * D_) / 256, 256, 0, stream>>>(feature, fps_i, nfeat);
    knn_kernel<<<8192, 256, 0, stream>>>(xyz, nxyz, knn, nullptr, nullptr, nullptr);
    std_partial<<<B_ * 64, 256, 0, stream>>>(feature, xyz, nxyz, nfeat, knn, stdpart);
    std_final<<<1, 64, 0, stream>>>(stdpart, invstd);
    mlp_kernel<0><<<B_ * S_, 256, 0, stream>>>(feature, xyz, nxyz, nfeat, knn, invstd,
                                               alpha, beta, w_tr, b_tr, w1, b1, w2, b2,
                                               bn_tr, bn_1, bnpart, out1);
    bn_finalize<<<64, 256, 0, stream>>>(bnpart, g_tr, be_tr, bn_tr);
    mlp_kernel<1><<<B_ * S_, 256, 0, stream>>>(feature, xyz, nxyz, nfeat, knn, invstd,
                                               alpha, beta, w_tr, b_tr, w1, b1, w2, b2,
                                               bn_tr, bn_1, bnpart, out1);
    bn_finalize<<<64, 256, 0, stream>>>(bnpart, g1, be1, bn_1);
    mlp_kernel<2><<<B_ * S_, 256, 0, stream>>>(feature, xyz, nxyz, nfeat, knn, invstd,
                                               alpha, beta, w_tr, b_tr, w1, b1, w2, b2,
                                               bn_tr, bn_1, bnpart, out1);
  }
}